// Round 1
// baseline (332.715 us; speedup 1.0000x reference)
//
#include <hip/hip_runtime.h>
#include <hip/hip_bf16.h>

#define BDIM 1024
#define LDIM 128
#define KDIM 16
#define DDIM 512
#define NFEAT 100000
#define NLAB 131072
#define NNEG 2048
#define NPOS (BDIM * KDIM)      /* 16384 */
#define NSUB (NPOS + NNEG)      /* 18432 */
#define EPSV 0.1f
#define CV 2.1f

// ---------------- init: build all_idx, zero accumulators ----------------
__global__ __launch_bounds__(256) void init_kernel(const int* __restrict__ labels,
                                                   const int* __restrict__ negs,
                                                   int* __restrict__ all_idx,
                                                   float* __restrict__ Zrow,
                                                   float* __restrict__ accum) {
    int j = blockIdx.x * 256 + threadIdx.x;
    if (j < NSUB) all_idx[j] = (j < NPOS) ? max(labels[j], 0) : negs[j - NPOS];
    if (j < BDIM) Zrow[j] = 0.f;
    if (j < 2) accum[j] = 0.f;
}

// ---------------- query: embed gather-sum + normalize ----------------
__global__ __launch_bounds__(256) void query_kernel(const int* __restrict__ indices,
                                                    const float* __restrict__ mask,
                                                    const float* __restrict__ embed,
                                                    float* __restrict__ query) {
    int b = blockIdx.x;
    int t = threadIdx.x;
    float acc0 = 0.f, acc1 = 0.f, msum = 0.f;
    for (int l = 0; l < LDIM; ++l) {
        int idx = indices[b * LDIM + l];
        float m = mask[b * LDIM + l];
        msum += m;
        const float* row = embed + (size_t)idx * DDIM;
        acc0 += m * row[t];
        acc1 += m * row[t + 256];
    }
    float denom = fmaxf(msum, 1.0f);
    acc0 /= denom; acc1 /= denom;

    float ss = acc0 * acc0 + acc1 * acc1;
    #pragma unroll
    for (int off = 32; off > 0; off >>= 1) ss += __shfl_down(ss, off, 64);
    __shared__ float red[4];
    __shared__ float snorm;
    int wid = t >> 6, lane = t & 63;
    if (lane == 0) red[wid] = ss;
    __syncthreads();
    if (t == 0) snorm = sqrtf(red[0] + red[1] + red[2] + red[3]);
    __syncthreads();
    float inv = 1.f / fmaxf(snorm, 1e-4f);
    query[(size_t)b * DDIM + t]        = acc0 * inv;
    query[(size_t)b * DDIM + t + 256]  = acc1 * inv;
}

// ---------------- W gather: WsubT[d][j] = W_kernel[d][all_idx[j]] ----------------
__global__ __launch_bounds__(256) void wgather_kernel(const int* __restrict__ all_idx,
                                                      const float* __restrict__ Wk,
                                                      float* __restrict__ WsubT) {
    int d = blockIdx.x;
    int chunk = blockIdx.y;                 // 8 chunks of 2304
    const float* row = Wk + (size_t)d * NLAB;
    float* orow = WsubT + (size_t)d * NSUB;
    int j0 = chunk * (NSUB / 8);
    int j1 = j0 + (NSUB / 8);
    for (int j = j0 + threadIdx.x; j < j1; j += 256)
        orow[j] = row[all_idx[j]];
}

// ---------------- column norms of WsubT ----------------
__global__ __launch_bounds__(256) void norms_kernel(const float* __restrict__ WsubT,
                                                    float* __restrict__ norms) {
    int j = blockIdx.x * 256 + threadIdx.x;
    if (j >= NSUB) return;
    float s = 0.f;
    for (int d = 0; d < DDIM; ++d) {
        float v = WsubT[(size_t)d * NSUB + j];
        s += v * v;
    }
    norms[j] = sqrtf(s);
}

// ---------------- positive scores (diagonal block) ----------------
__global__ __launch_bounds__(256) void pos_kernel(const float* __restrict__ query,
                                                  const float* __restrict__ WsubT,
                                                  const float* __restrict__ norms,
                                                  float* __restrict__ pos_scores,
                                                  float* __restrict__ Zrow) {
    int j = blockIdx.x * 256 + threadIdx.x;   // 0..NPOS
    int b = j >> 4;
    const float* q = query + (size_t)b * DDIM;
    float acc = 0.f;
    #pragma unroll 4
    for (int d = 0; d < DDIM; ++d) acc += q[d] * WsubT[(size_t)d * NSUB + j];
    float dot = acc / fmaxf(norms[j], 1e-4f);
    dot = fminf(fmaxf(dot, -0.999f), 0.999f);
    float sc = dot * dot / fmaxf(CV - 2.f * dot, EPSV);
    pos_scores[j] = sc;
    atomicAdd(&Zrow[b], sc);
}

// ---------------- negative GEMM + fused score + row-sum ----------------
#define BM 64
#define BN 64
#define BK 32
__global__ __launch_bounds__(256) void neg_kernel(const float* __restrict__ query,
                                                  const float* __restrict__ WsubT,
                                                  const float* __restrict__ norms,
                                                  float* __restrict__ Zrow) {
    __shared__ float As[BK][BM + 1];   // k-major, pad to 65 to spread store banks
    __shared__ float Bs[BK][BN];
    __shared__ float rowsum[BM];
    int t = threadIdx.x;
    int bm0 = blockIdx.x * BM;
    int nb0 = blockIdx.y * BN;
    int tx = t & 15, ty = t >> 4;
    float c[4][4] = {{0.f}};

    int ar = t >> 3;            // 0..31
    int ak = (t & 7) * 4;       // 0..28
    int bk = t >> 4;            // 0..15
    int bn = (t & 15) * 4;      // 0..60

    for (int k0 = 0; k0 < DDIM; k0 += BK) {
        float4 a0 = *(const float4*)&query[(size_t)(bm0 + ar)      * DDIM + k0 + ak];
        float4 a1 = *(const float4*)&query[(size_t)(bm0 + ar + 32) * DDIM + k0 + ak];
        float4 b0 = *(const float4*)&WsubT[(size_t)(k0 + bk)      * NSUB + NPOS + nb0 + bn];
        float4 b1 = *(const float4*)&WsubT[(size_t)(k0 + bk + 16) * NSUB + NPOS + nb0 + bn];
        __syncthreads();
        As[ak + 0][ar] = a0.x; As[ak + 1][ar] = a0.y; As[ak + 2][ar] = a0.z; As[ak + 3][ar] = a0.w;
        As[ak + 0][ar + 32] = a1.x; As[ak + 1][ar + 32] = a1.y; As[ak + 2][ar + 32] = a1.z; As[ak + 3][ar + 32] = a1.w;
        *(float4*)&Bs[bk][bn]      = b0;
        *(float4*)&Bs[bk + 16][bn] = b1;
        __syncthreads();
        #pragma unroll
        for (int kk = 0; kk < BK; ++kk) {
            float av[4], bv[4];
            #pragma unroll
            for (int i = 0; i < 4; ++i) av[i] = As[kk][ty * 4 + i];
            #pragma unroll
            for (int i = 0; i < 4; ++i) bv[i] = Bs[kk][tx * 4 + i];
            #pragma unroll
            for (int i = 0; i < 4; ++i)
                #pragma unroll
                for (int jn = 0; jn < 4; ++jn)
                    c[i][jn] += av[i] * bv[jn];
        }
    }

    float nrm[4];
    #pragma unroll
    for (int jn = 0; jn < 4; ++jn) nrm[jn] = fmaxf(norms[NPOS + nb0 + tx * 4 + jn], 1e-4f);

    __syncthreads();
    if (t < BM) rowsum[t] = 0.f;
    __syncthreads();
    #pragma unroll
    for (int i = 0; i < 4; ++i) {
        float s = 0.f;
        #pragma unroll
        for (int jn = 0; jn < 4; ++jn) {
            float dot = c[i][jn] / nrm[jn];
            dot = fminf(fmaxf(dot, -0.999f), 0.999f);
            s += dot * dot / fmaxf(CV - 2.f * dot, EPSV);
        }
        atomicAdd(&rowsum[ty * 4 + i], s);
    }
    __syncthreads();
    if (t < BM) atomicAdd(&Zrow[bm0 + t], rowsum[t]);
}

// ---------------- finalize ----------------
__global__ __launch_bounds__(256) void finalize_kernel(const float* __restrict__ pos_scores,
                                                       const float* __restrict__ label_mask,
                                                       const float* __restrict__ Zrow,
                                                       float* __restrict__ accum) {
    int j = blockIdx.x * 256 + threadIdx.x;  // < NPOS
    int b = j >> 4;
    float lm = label_mask[j];
    float logZ = logf(Zrow[b] + (float)(KDIM + NNEG) * 1e-8f);
    float v = lm * (logf(pos_scores[j] + 1e-8f) - logZ);
    #pragma unroll
    for (int off = 32; off > 0; off >>= 1) {
        v  += __shfl_down(v, off, 64);
        lm += __shfl_down(lm, off, 64);
    }
    __shared__ float rv[4], rl[4];
    int wid = threadIdx.x >> 6, lane = threadIdx.x & 63;
    if (lane == 0) { rv[wid] = v; rl[wid] = lm; }
    __syncthreads();
    if (threadIdx.x == 0) {
        atomicAdd(&accum[0], rv[0] + rv[1] + rv[2] + rv[3]);
        atomicAdd(&accum[1], rl[0] + rl[1] + rl[2] + rl[3]);
    }
}

__global__ void writeout_kernel(const float* __restrict__ accum, float* __restrict__ out) {
    out[0] = -accum[0] / (accum[1] + 1e-6f);
}

extern "C" void kernel_launch(void* const* d_in, const int* in_sizes, int n_in,
                              void* d_out, int out_size, void* d_ws, size_t ws_size,
                              hipStream_t stream) {
    const int*   indices    = (const int*)  d_in[0];
    const float* mask       = (const float*)d_in[1];
    const int*   labels     = (const int*)  d_in[2];
    const float* label_mask = (const float*)d_in[3];
    const int*   negs       = (const int*)  d_in[4];
    const float* embed      = (const float*)d_in[5];
    const float* Wk         = (const float*)d_in[6];
    float* out = (float*)d_out;

    // workspace layout
    float* WsubT      = (float*)d_ws;              // 512*18432
    float* query      = WsubT + (size_t)DDIM * NSUB;
    int*   all_idx    = (int*)(query + (size_t)BDIM * DDIM);
    float* norms      = (float*)(all_idx + NSUB);
    float* pos_scores = norms + NSUB;
    float* Zrow       = pos_scores + NPOS;
    float* accum      = Zrow + BDIM;

    init_kernel<<<(NSUB + 255) / 256, 256, 0, stream>>>(labels, negs, all_idx, Zrow, accum);
    query_kernel<<<BDIM, 256, 0, stream>>>(indices, mask, embed, query);
    wgather_kernel<<<dim3(DDIM, 8), 256, 0, stream>>>(all_idx, Wk, WsubT);
    norms_kernel<<<NSUB / 256, 256, 0, stream>>>(WsubT, norms);
    pos_kernel<<<NPOS / 256, 256, 0, stream>>>(query, WsubT, norms, pos_scores, Zrow);
    neg_kernel<<<dim3(BDIM / BM, NNEG / BN), 256, 0, stream>>>(query, WsubT, norms, Zrow);
    finalize_kernel<<<NPOS / 256, 256, 0, stream>>>(pos_scores, label_mask, Zrow, accum);
    writeout_kernel<<<1, 1, 0, stream>>>(accum, out);
}